// Round 1
// baseline (268.850 us; speedup 1.0000x reference)
//
#include <hip/hip_runtime.h>
#include <math.h>

#define BB 64
#define LL 512
#define DD 512
#define CC 50
#define NC 100        // combined cols (head1 | head2)
#define NCP 112       // padded W tile width
#define TM 64         // rows per block
#define KT 64         // K tile
#define KTP 68        // padded A tile stride (conflict-free-ish b128 reads)

// ---------------------------------------------------------------------------
// k_prep: per-batch block. Phase 1: sbj_vec = masked span mean of text_vec.
// Phase 2: s_comb[b][cc] = sbj_vec @ W_h[D2:] + bias_h  (cc<50: start head).
// Also zeroes the global loss accumulators ws[0], ws[1].
// ---------------------------------------------------------------------------
__global__ __launch_bounds__(256) void k_prep(
    const float* __restrict__ tv, const int* __restrict__ sbj_bound,
    const float* __restrict__ Wst, const float* __restrict__ bst,
    const float* __restrict__ Wen, const float* __restrict__ ben,
    float* __restrict__ ws)
{
    __shared__ float sbj[DD];
    const int b = blockIdx.x;
    const int t = threadIdx.x;
    const int start = sbj_bound[2 * b];
    const int end   = sbj_bound[2 * b + 1];
    const float inv = 1.0f / (float)(end - start + 1);

    const float* base = tv + (size_t)b * LL * DD;
    float a0 = 0.f, a1 = 0.f, a2 = 0.f, a3 = 0.f;
    int l = start;
    for (; l + 1 <= end; l += 2) {
        const float* p0 = base + (size_t)l * DD;
        const float* p1 = p0 + DD;
        a0 += p0[t];       a1 += p0[t + 256];
        a2 += p1[t];       a3 += p1[t + 256];
    }
    if (l <= end) {
        const float* p0 = base + (size_t)l * DD;
        a0 += p0[t];       a1 += p0[t + 256];
    }
    sbj[t]       = (a0 + a2) * inv;
    sbj[t + 256] = (a1 + a3) * inv;
    __syncthreads();

    if (t < NC) {
        const int head = (t < CC) ? 0 : 1;
        const int c = head ? (t - CC) : t;
        const float* W = head ? Wen : Wst;
        const float bias = head ? ben[c] : bst[c];
        const float* Wp = W + (size_t)DD * CC + c;  // lower half, column c
        float s0 = 0.f, s1 = 0.f, s2 = 0.f, s3 = 0.f;
        for (int d = 0; d < DD; d += 4) {
            s0 = fmaf(sbj[d + 0], Wp[(size_t)(d + 0) * CC], s0);
            s1 = fmaf(sbj[d + 1], Wp[(size_t)(d + 1) * CC], s1);
            s2 = fmaf(sbj[d + 2], Wp[(size_t)(d + 2) * CC], s2);
            s3 = fmaf(sbj[d + 3], Wp[(size_t)(d + 3) * CC], s3);
        }
        ws[16 + b * NC + t] = bias + ((s0 + s1) + (s2 + s3));
    }
    if (b == 0 && t == 0) { ws[0] = 0.0f; ws[1] = 0.0f; }
}

// ---------------------------------------------------------------------------
// k_main: tiled GEMM (TM=64 rows x 100 cols, K=512 in KT=64 tiles) with fused
// log-softmax + masked-CE epilogue. One atomicAdd pair per block.
// Thread layout: tc = tid&15 (col group, cc = tc+16u), tr = tid>>4 (4 rows).
// Row-group = 16 consecutive lanes -> shfl_xor(width=16) reductions.
// ---------------------------------------------------------------------------
__global__ __launch_bounds__(256) void k_main(
    const float* __restrict__ tv,
    const int* __restrict__ mask,
    const int* __restrict__ obj_s, const int* __restrict__ obj_e,
    const float* __restrict__ Wst, const float* __restrict__ Wen,
    const float* __restrict__ wsro, float* __restrict__ wsacc)
{
    __shared__ __align__(16) float As[TM][KTP];
    __shared__ __align__(16) float Wt[KT][NCP];
    __shared__ float scomb[NCP];
    __shared__ float red[8];

    const int t  = threadIdx.x;
    const int m0 = blockIdx.x * TM;
    const int b  = m0 / LL;           // 8 blocks per batch row-range
    const int tc = t & 15;
    const int tr = t >> 4;

    if (t < NCP) scomb[t] = (t < NC) ? wsro[16 + b * NC + t] : 0.0f;
    // zero the W-tile pad columns once (never rewritten)
    for (int idx = t; idx < KT * (NCP - NC); idx += 256)
        Wt[idx / (NCP - NC)][NC + idx % (NCP - NC)] = 0.0f;

    float acc[4][7];
#pragma unroll
    for (int i = 0; i < 4; i++)
#pragma unroll
        for (int u = 0; u < 7; u++) acc[i][u] = 0.0f;

    for (int k0 = 0; k0 < DD; k0 += KT) {
        // stage A tile: 64 rows x 64 k  (1024 float4 by 256 threads)
#pragma unroll
        for (int i = 0; i < 4; i++) {
            int idx = t + i * 256;
            int m  = idx >> 4;
            int kq = idx & 15;
            float4 v = *(const float4*)(tv + (size_t)(m0 + m) * DD + k0 + kq * 4);
            *(float4*)&As[m][kq * 4] = v;
        }
        // stage W tile: 64 k x (50 | 50)
        for (int idx = t; idx < KT * CC; idx += 256) {
            int k = idx / CC;
            int c = idx - k * CC;
            Wt[k][c]      = Wst[(size_t)(k0 + k) * CC + c];
            Wt[k][c + CC] = Wen[(size_t)(k0 + k) * CC + c];
        }
        __syncthreads();

        for (int k = 0; k < KT; k += 4) {
            float a[4][4];
#pragma unroll
            for (int i = 0; i < 4; i++) {
                float4 v = *(const float4*)&As[tr * 4 + i][k];
                a[i][0] = v.x; a[i][1] = v.y; a[i][2] = v.z; a[i][3] = v.w;
            }
#pragma unroll
            for (int j = 0; j < 4; j++) {
                float w[7];
#pragma unroll
                for (int u = 0; u < 7; u++) w[u] = Wt[k + j][tc + 16 * u];
#pragma unroll
                for (int i = 0; i < 4; i++)
#pragma unroll
                    for (int u = 0; u < 7; u++)
                        acc[i][u] = fmaf(a[i][j], w[u], acc[i][u]);
            }
        }
        __syncthreads();
    }

    // ---- fused CE epilogue ----
    float loss_local = 0.0f, cnt_local = 0.0f;
#pragma unroll
    for (int i = 0; i < 4; i++) {
        const int m = m0 + tr * 4 + i;
        const int l = m & (LL - 1);
        float lg[7];
#pragma unroll
        for (int u = 0; u < 7; u++) lg[u] = acc[i][u] + scomb[tc + 16 * u];
        // head1: cc in [0,50) -> u=0,1,2 always; u=3 iff tc<2
        // head2: cc in [50,100) -> u=3 iff tc>=2; u=4,5 always; u=6 iff tc<4
        float m1 = fmaxf(fmaxf(lg[0], lg[1]), lg[2]);
        if (tc < 2) m1 = fmaxf(m1, lg[3]);
        float m2 = fmaxf(lg[4], lg[5]);
        if (tc >= 2) m2 = fmaxf(m2, lg[3]);
        if (tc < 4)  m2 = fmaxf(m2, lg[6]);
#pragma unroll
        for (int off = 1; off < 16; off <<= 1) {
            m1 = fmaxf(m1, __shfl_xor(m1, off, 16));
            m2 = fmaxf(m2, __shfl_xor(m2, off, 16));
        }
        float e1 = expf(lg[0] - m1) + expf(lg[1] - m1) + expf(lg[2] - m1)
                 + ((tc < 2) ? expf(lg[3] - m1) : 0.0f);
        float e2 = expf(lg[4] - m2) + expf(lg[5] - m2)
                 + ((tc >= 2) ? expf(lg[3] - m2) : 0.0f)
                 + ((tc < 4)  ? expf(lg[6] - m2) : 0.0f);
        const int lab1 = obj_s[b * LL + l];
        const int lab2 = obj_e[b * LL + l] + CC;
        float t1 = 0.0f, t2 = 0.0f;
#pragma unroll
        for (int u = 0; u < 7; u++) {
            const int cc = tc + 16 * u;
            if (cc == lab1) t1 = lg[u];
            if (cc == lab2) t2 = lg[u];
        }
#pragma unroll
        for (int off = 1; off < 16; off <<= 1) {
            e1 += __shfl_xor(e1, off, 16);
            e2 += __shfl_xor(e2, off, 16);
            t1 += __shfl_xor(t1, off, 16);
            t2 += __shfl_xor(t2, off, 16);
        }
        if (tc == 0) {
            const int mk = (mask[b * LL + l] != 0) ? 1 : 0;
            const float nll = (m1 + logf(e1) - t1) + (m2 + logf(e2) - t2);
            loss_local += mk ? nll : 0.0f;
            cnt_local  += (float)mk;
        }
    }
    // block reduction: full-wave sum then cross-wave via LDS
#pragma unroll
    for (int off = 1; off < 64; off <<= 1) {
        loss_local += __shfl_xor(loss_local, off);
        cnt_local  += __shfl_xor(cnt_local, off);
    }
    if ((t & 63) == 0) { red[(t >> 6) * 2] = loss_local; red[(t >> 6) * 2 + 1] = cnt_local; }
    __syncthreads();
    if (t == 0) {
        float Ls = red[0] + red[2] + red[4] + red[6];
        float Cs = red[1] + red[3] + red[5] + red[7];
        atomicAdd(&wsacc[0], Ls);
        atomicAdd(&wsacc[1], Cs);
    }
}

__global__ void k_final(const float* __restrict__ ws, float* __restrict__ out) {
    out[0] = ws[0] / ws[1];
}

extern "C" void kernel_launch(void* const* d_in, const int* in_sizes, int n_in,
                              void* d_out, int out_size, void* d_ws, size_t ws_size,
                              hipStream_t stream) {
    const float* tv   = (const float*)d_in[0];
    const int*   mask = (const int*)d_in[1];
    const int*   sbj  = (const int*)d_in[2];
    const int*   objs = (const int*)d_in[3];
    const int*   obje = (const int*)d_in[4];
    const float* Wst  = (const float*)d_in[5];
    const float* bst  = (const float*)d_in[6];
    const float* Wen  = (const float*)d_in[7];
    const float* ben  = (const float*)d_in[8];
    float* out = (float*)d_out;
    float* ws  = (float*)d_ws;

    k_prep<<<BB, 256, 0, stream>>>(tv, sbj, Wst, bst, Wen, ben, ws);
    k_main<<<(BB * LL) / TM, 256, 0, stream>>>(tv, mask, objs, obje, Wst, Wen, ws, ws);
    k_final<<<1, 1, 0, stream>>>(ws, out);
}

// Round 3
// 176.760 us; speedup vs baseline: 1.5210x; 1.5210x over previous
//
#include <hip/hip_runtime.h>
#include <math.h>

#define BB 64
#define LL 512
#define DD 512
#define CC 50
#define NC 100        // combined cols (head1 | head2)
#define NCP 112       // padded col count (7 x 16)
#define TM 64         // rows per k_main block
#define KT 128        // K tile
#define AST 136       // A LDS row stride (bf16 units)
#define WST 136       // W LDS row stride (bf16 units)

// ws layout (float units):
//   [0] loss  [1] cnt
//   [16 .. 16+32768)          sbj accumulators  (b*512 + d)
//   [32784 .. 32784+7168)     scomb             (b*112 + cc)
//   float offset 39952 (byte 159808, 16B-aligned): Wb bf16 [112][512]
#define WS_SBJ   16
#define WS_SCOMB 32784
#define WS_WB    39952

typedef __attribute__((ext_vector_type(8))) short bf16x8;
typedef __attribute__((ext_vector_type(4))) float f32x4;

static __device__ __forceinline__ unsigned short f2bf(float x) {
    unsigned int u = __float_as_uint(x);
    u += 0x7FFFu + ((u >> 16) & 1u);          // RNE
    return (unsigned short)(u >> 16);
}

// ---------------------------------------------------------------------------
// k0: blocks [0,32): zero loss accumulators + sbj accumulator region.
//     blocks [32,88): build Wb[n][k] = W_h[k][c] (top half of W, k<512),
//     bf16, n in [0,112) with pad rows zeroed.
// ---------------------------------------------------------------------------
__global__ __launch_bounds__(256) void k0(
    const float* __restrict__ Wst, const float* __restrict__ Wen,
    float* __restrict__ ws)
{
    const int t = threadIdx.x;
    const int blk = blockIdx.x;
    if (blk < 32) {
        ((float4*)(ws + WS_SBJ))[blk * 256 + t] = make_float4(0.f, 0.f, 0.f, 0.f);
        if (blk == 0 && t == 0) { ws[0] = 0.0f; ws[1] = 0.0f; }
    } else {
        unsigned short* Wb = (unsigned short*)(ws + WS_WB);
        const int idx = (blk - 32) * 256 + t;   // [0, 14336)
        const int n  = idx >> 7;                // 0..111
        const int k  = (idx & 127) * 4;
        unsigned short v[4];
        if (n < NC) {
            const float* W = (n < CC) ? Wst : Wen;
            const int c = (n < CC) ? n : n - CC;
#pragma unroll
            for (int j = 0; j < 4; j++)
                v[j] = f2bf(W[(size_t)(k + j) * CC + c]);
        } else {
            v[0] = v[1] = v[2] = v[3] = 0;
        }
        *(ushort4*)(Wb + (size_t)n * DD + k) = make_ushort4(v[0], v[1], v[2], v[3]);
    }
}

// ---------------------------------------------------------------------------
// k_span: grid 64*8. Block (b,seg) sums rows [seg*64, seg*64+64) ∩ [start,end]
// into ws_sbj[b][*] via atomicAdd. Each thread owns 2 d-columns.
// ---------------------------------------------------------------------------
__global__ __launch_bounds__(256) void k_span(
    const float* __restrict__ tv, const int* __restrict__ sbj_bound,
    float* __restrict__ ws)
{
    const int b = blockIdx.x >> 3;
    const int seg = blockIdx.x & 7;
    const int start = sbj_bound[2 * b];
    const int end   = sbj_bound[2 * b + 1];
    int r0 = seg * 64;       if (r0 < start) r0 = start;
    int r1 = seg * 64 + 63;  if (r1 > end) r1 = end;
    if (r0 > r1) return;
    const int t = threadIdx.x;
    const float* base = tv + ((size_t)b * LL + r0) * DD;
    float s0 = 0.f, s1 = 0.f;
    for (int r = r0; r <= r1; ++r, base += DD) {
        s0 += base[t];
        s1 += base[t + 256];
    }
    atomicAdd(ws + WS_SBJ + b * DD + t,       s0);
    atomicAdd(ws + WS_SBJ + b * DD + t + 256, s1);
}

// ---------------------------------------------------------------------------
// k_scomb: per-batch block. scomb[b][cc] = (sbj/count) @ W_h[D2:,c] + bias_h.
// ---------------------------------------------------------------------------
__global__ __launch_bounds__(256) void k_scomb(
    const int* __restrict__ sbj_bound,
    const float* __restrict__ Wst, const float* __restrict__ bst,
    const float* __restrict__ Wen, const float* __restrict__ ben,
    float* __restrict__ ws)
{
    __shared__ float sbj[DD];
    const int b = blockIdx.x;
    const int t = threadIdx.x;
    const float inv = 1.0f / (float)(sbj_bound[2 * b + 1] - sbj_bound[2 * b] + 1);
    sbj[t]       = ws[WS_SBJ + b * DD + t] * inv;
    sbj[t + 256] = ws[WS_SBJ + b * DD + t + 256] * inv;
    __syncthreads();
    if (t < NC) {
        const int head = (t < CC) ? 0 : 1;
        const int c = head ? (t - CC) : t;
        const float* W = head ? Wen : Wst;
        const float bias = head ? ben[c] : bst[c];
        const float* Wp = W + (size_t)DD * CC + c;   // lower half, column c
        float s0 = 0.f, s1 = 0.f, s2 = 0.f, s3 = 0.f;
        for (int d = 0; d < DD; d += 4) {
            s0 = fmaf(sbj[d + 0], Wp[(size_t)(d + 0) * CC], s0);
            s1 = fmaf(sbj[d + 1], Wp[(size_t)(d + 1) * CC], s1);
            s2 = fmaf(sbj[d + 2], Wp[(size_t)(d + 2) * CC], s2);
            s3 = fmaf(sbj[d + 3], Wp[(size_t)(d + 3) * CC], s3);
        }
        ws[WS_SCOMB + b * NCP + t] = bias + ((s0 + s1) + (s2 + s3));
    }
}

// ---------------------------------------------------------------------------
// k_main: bf16 MFMA GEMM (TM=64 rows x 112 cols, K=512 in 4 tiles of 128)
// + fused log-softmax/masked-CE epilogue. 4 waves, each 16 rows x 7 col-tiles.
// ---------------------------------------------------------------------------
__global__ __launch_bounds__(256) void k_main(
    const float* __restrict__ tv,
    const int* __restrict__ mask,
    const int* __restrict__ obj_s, const int* __restrict__ obj_e,
    const float* __restrict__ ws)
{
    __shared__ __align__(16) unsigned short As[TM * AST];
    __shared__ __align__(16) unsigned short Wt[NCP * WST];
    __shared__ float scomb[NCP];
    __shared__ float red[8];

    const int t  = threadIdx.x;
    const int m0 = blockIdx.x * TM;
    const int b  = m0 >> 9;               // 8 blocks per batch
    const int wv = t >> 6;
    const int ln = t & 63;
    const int tc = ln & 15;
    const int quad = ln >> 4;
    const unsigned short* Wb = (const unsigned short*)(ws + WS_WB);

    if (t < NCP) scomb[t] = (t < NC) ? ws[WS_SCOMB + b * NCP + t] : 0.0f;

    f32x4 acc[7];
#pragma unroll
    for (int u = 0; u < 7; u++) acc[u] = (f32x4)(0.0f);

    const unsigned short* Afrag = As + (wv * 16 + tc) * AST + quad * 8;
    const unsigned short* Wfrag = Wt + tc * WST + quad * 8;

    for (int k0 = 0; k0 < DD; k0 += KT) {
        // stage A tile: 64 rows x 128 k, f32 -> bf16 (coalesced float4 reads)
#pragma unroll
        for (int i = 0; i < 8; i++) {
            const int idx = t + 256 * i;          // [0, 2048)
            const int row = idx >> 5;
            const int kq  = idx & 31;             // float4 index within 128 k
            float4 v = *(const float4*)(tv + ((size_t)(m0 + row) * DD) + k0 + kq * 4);
            *(ushort4*)(As + row * AST + kq * 4) =
                make_ushort4(f2bf(v.x), f2bf(v.y), f2bf(v.z), f2bf(v.w));
        }
        // stage W tile: 112 rows x 128 k — FIXED: 8-short (16B) copies so the
        // full 128-k row is covered (R2 bug: ushort4 at stride 8 left gaps)
#pragma unroll
        for (int i = 0; i < 7; i++) {
            const int idx = t + 256 * i;          // [0, 1792)
            const int n   = idx >> 4;
            const int seg = idx & 15;             // 16B segment = 8 bf16
            *(bf16x8*)(Wt + n * WST + seg * 8) =
                *(const bf16x8*)(Wb + (size_t)n * DD + k0 + seg * 8);
        }
        __syncthreads();

#pragma unroll
        for (int kk = 0; kk < KT; kk += 32) {
            bf16x8 af = *(const bf16x8*)(Afrag + kk);
#pragma unroll
            for (int u = 0; u < 7; u++) {
                bf16x8 bf = *(const bf16x8*)(Wfrag + u * 16 * WST + kk);
                acc[u] = __builtin_amdgcn_mfma_f32_16x16x32_bf16(af, bf, acc[u], 0, 0, 0);
            }
        }
        __syncthreads();
    }

    // ---- fused CE epilogue ----
    // C/D layout: col = lane&15, row = quad*4 + reg  (per 16-row wave tile)
    float loss_local = 0.0f, cnt_local = 0.0f;
#pragma unroll
    for (int i = 0; i < 4; i++) {
        const int m = m0 + wv * 16 + quad * 4 + i;
        const int l = m & (LL - 1);
        float lg[7];
#pragma unroll
        for (int u = 0; u < 7; u++) lg[u] = acc[u][i] + scomb[u * 16 + tc];
        // head1: cc in [0,50): u=0,1,2 always; u=3 iff tc<2
        // head2: cc in [50,100): u=3 iff tc>=2; u=4,5 always; u=6 iff tc<4
        float m1 = fmaxf(fmaxf(lg[0], lg[1]), lg[2]);
        if (tc < 2) m1 = fmaxf(m1, lg[3]);
        float m2 = fmaxf(lg[4], lg[5]);
        if (tc >= 2) m2 = fmaxf(m2, lg[3]);
        if (tc < 4)  m2 = fmaxf(m2, lg[6]);
#pragma unroll
        for (int off = 1; off < 16; off <<= 1) {
            m1 = fmaxf(m1, __shfl_xor(m1, off, 16));
            m2 = fmaxf(m2, __shfl_xor(m2, off, 16));
        }
        float e1 = expf(lg[0] - m1) + expf(lg[1] - m1) + expf(lg[2] - m1)
                 + ((tc < 2) ? expf(lg[3] - m1) : 0.0f);
        float e2 = expf(lg[4] - m2) + expf(lg[5] - m2)
                 + ((tc >= 2) ? expf(lg[3] - m2) : 0.0f)
                 + ((tc < 4)  ? expf(lg[6] - m2) : 0.0f);
        const int lab1 = obj_s[b * LL + l];
        const int lab2 = obj_e[b * LL + l] + CC;
        float t1 = 0.0f, t2 = 0.0f;
#pragma unroll
        for (int u = 0; u < 7; u++) {
            const int cc = u * 16 + tc;
            if (cc == lab1) t1 = lg[u];
            if (cc == lab2) t2 = lg[u];
        }
#pragma unroll
        for (int off = 1; off < 16; off <<= 1) {
            e1 += __shfl_xor(e1, off, 16);
            e2 += __shfl_xor(e2, off, 16);
            t1 += __shfl_xor(t1, off, 16);
            t2 += __shfl_xor(t2, off, 16);
        }
        if (tc == 0) {
            const int mk = (mask[b * LL + l] != 0) ? 1 : 0;
            const float nll = (m1 + logf(e1) - t1) + (m2 + logf(e2) - t2);
            loss_local += mk ? nll : 0.0f;
            cnt_local  += (float)mk;
        }
    }
#pragma unroll
    for (int off = 1; off < 64; off <<= 1) {
        loss_local += __shfl_xor(loss_local, off);
        cnt_local  += __shfl_xor(cnt_local, off);
    }
    if (ln == 0) { red[wv * 2] = loss_local; red[wv * 2 + 1] = cnt_local; }
    __syncthreads();
    if (t == 0) {
        float* wsacc = (float*)ws;   // accumulators live in ws
        atomicAdd(&wsacc[0], red[0] + red[2] + red[4] + red[6]);
        atomicAdd(&wsacc[1], red[1] + red[3] + red[5] + red[7]);
    }
}

__global__ void k_final(const float* __restrict__ ws, float* __restrict__ out) {
    out[0] = ws[0] / ws[1];
}

extern "C" void kernel_launch(void* const* d_in, const int* in_sizes, int n_in,
                              void* d_out, int out_size, void* d_ws, size_t ws_size,
                              hipStream_t stream) {
    const float* tv   = (const float*)d_in[0];
    const int*   mask = (const int*)d_in[1];
    const int*   sbj  = (const int*)d_in[2];
    const int*   objs = (const int*)d_in[3];
    const int*   obje = (const int*)d_in[4];
    const float* Wst  = (const float*)d_in[5];
    const float* bst  = (const float*)d_in[6];
    const float* Wen  = (const float*)d_in[7];
    const float* ben  = (const float*)d_in[8];
    float* out = (float*)d_out;
    float* ws  = (float*)d_ws;

    k0<<<88, 256, 0, stream>>>(Wst, Wen, ws);
    k_span<<<BB * 8, 256, 0, stream>>>(tv, sbj, ws);
    k_scomb<<<BB, 256, 0, stream>>>(sbj, Wst, bst, Wen, ben, ws);
    k_main<<<(BB * LL) / TM, 256, 0, stream>>>(tv, mask, objs, obje, ws);
    k_final<<<1, 1, 0, stream>>>(ws, out);
}